// Round 6
// baseline (1599.601 us; speedup 1.0000x reference)
//
#include <hip/hip_runtime.h>
#include <math.h>

#define BB 8
#define SS 1024
#define DM 512
#define DK 64
#define NITER 40
#define SPARS 0.05f
#define NPOW 64
#define TM 8
#define CHK 32
#define APAD 1028

// ---------------- projections: Q/8, K/8, V ----------------
__global__ __launch_bounds__(256) void proj_kernel(
    const float* __restrict__ x,
    const float* __restrict__ Wq, const float* __restrict__ bq,
    const float* __restrict__ Wk, const float* __restrict__ bk,
    const float* __restrict__ Wv, const float* __restrict__ bv,
    float* __restrict__ qs, float* __restrict__ ks, float* __restrict__ vv)
{
    __shared__ float xs[16][DM];
    int row0 = blockIdx.x * 16;
    int tid = threadIdx.x;
    const float4* xg = (const float4*)(x + (size_t)row0 * DM);
    float4* xs4 = (float4*)&xs[0][0];
    for (int i = tid; i < 16 * DM / 4; i += 256) xs4[i] = xg[i];
    __syncthreads();
    int lane = tid & 63, w = tid >> 6;  // 4 waves, 4 rows each
    float aq[4] = {0,0,0,0}, ak[4] = {0,0,0,0}, av[4] = {0,0,0,0};
    for (int i = 0; i < DM; ++i) {
        float wq = Wq[i*DK + lane], wk = Wk[i*DK + lane], wv = Wv[i*DK + lane];
        #pragma unroll
        for (int r = 0; r < 4; ++r) {
            float xv = xs[w*4 + r][i];
            aq[r] = fmaf(xv, wq, aq[r]);
            ak[r] = fmaf(xv, wk, ak[r]);
            av[r] = fmaf(xv, wv, av[r]);
        }
    }
    float bqv = bq[lane], bkv = bk[lane], bvv = bv[lane];
    #pragma unroll
    for (int r = 0; r < 4; ++r) {
        size_t o = (size_t)(row0 + w*4 + r) * DK + lane;
        qs[o] = (aq[r] + bqv) * 0.125f;
        ks[o] = (ak[r] + bkv) * 0.125f;
        vv[o] = av[r] + bvv;
    }
}

// ---------------- chunk Gram sums (chunk = 32) ----------------
__global__ __launch_bounds__(64) void gram_kernel(
    const float* __restrict__ ks, float* __restrict__ gp)
{
    int bc = blockIdx.x; int b = bc >> 5, c = bc & 31;
    __shared__ float kc[32][DK];
    int lane = threadIdx.x;
    const float* src = ks + ((size_t)b*SS + c*32) * DK;
    for (int i = lane; i < 32*DK; i += 64) ((float*)kc)[i] = src[i];
    __syncthreads();
    float row[DK];
    #pragma unroll
    for (int j = 0; j < DK; ++j) row[j] = 0.f;
    for (int s = 0; s < 32; ++s) {
        float ki = kc[s][lane];
        const float4* kr = (const float4*)&kc[s][0];
        #pragma unroll
        for (int j4 = 0; j4 < 16; ++j4) {
            float4 kv = kr[j4];
            row[4*j4+0] = fmaf(ki, kv.x, row[4*j4+0]);
            row[4*j4+1] = fmaf(ki, kv.y, row[4*j4+1]);
            row[4*j4+2] = fmaf(ki, kv.z, row[4*j4+2]);
            row[4*j4+3] = fmaf(ki, kv.w, row[4*j4+3]);
        }
    }
    float* dst = gp + (((size_t)b*32 + c) * DK + lane) * DK;
    #pragma unroll
    for (int j = 0; j < DK; ++j) dst[j] = row[j];
}

// ---------------- exclusive prefix over chunks ----------------
__global__ __launch_bounds__(256) void prefix_kernel(float* __restrict__ gp)
{
    int b = blockIdx.x; int tid = threadIdx.x;
    float run[16];
    #pragma unroll
    for (int e = 0; e < 16; ++e) run[e] = 0.f;
    for (int c = 0; c < 32; ++c) {
        float* p = gp + ((size_t)b*32 + c) * 4096 + tid * 16;
        #pragma unroll
        for (int e = 0; e < 16; ++e) { float t = p[e]; p[e] = run[e]; run[e] += t; }
    }
}

// ---------------- per-(b,t) top eigenvalue -> eta ----------------
__global__ __launch_bounds__(64) void eigen_kernel(
    const float* __restrict__ ks, const float* __restrict__ gp,
    float* __restrict__ eta)
{
    int bt = blockIdx.x; int b = bt >> 10, t = bt & (SS - 1);
    int c = t >> 5;
    int lane = threadIdx.x;
    __shared__ float kc[32][DK];
    __shared__ float vsh[DK];
    float row[DK];
    const float4* gr = (const float4*)(gp + (((size_t)b*32 + c) * DK + lane) * DK);
    #pragma unroll
    for (int j4 = 0; j4 < 16; ++j4) {
        float4 g = gr[j4];
        row[4*j4] = g.x; row[4*j4+1] = g.y; row[4*j4+2] = g.z; row[4*j4+3] = g.w;
    }
    const float* src = ks + ((size_t)b*SS + c*32) * DK;
    for (int i = lane; i < 32*DK; i += 64) ((float*)kc)[i] = src[i];
    __syncthreads();
    int nrow = t - c*32 + 1;
    for (int s = 0; s < nrow; ++s) {
        float ki = kc[s][lane];
        const float4* kr = (const float4*)&kc[s][0];
        #pragma unroll
        for (int j4 = 0; j4 < 16; ++j4) {
            float4 kv = kr[j4];
            row[4*j4+0] = fmaf(ki, kv.x, row[4*j4+0]);
            row[4*j4+1] = fmaf(ki, kv.y, row[4*j4+1]);
            row[4*j4+2] = fmaf(ki, kv.z, row[4*j4+2]);
            row[4*j4+3] = fmaf(ki, kv.w, row[4*j4+3]);
        }
    }
    // power iteration, v init = ones (y = G*1)
    float y;
    {
        float a0 = 0, a1 = 0, a2 = 0, a3 = 0;
        #pragma unroll
        for (int j = 0; j < DK; j += 4) {
            a0 += row[j]; a1 += row[j+1]; a2 += row[j+2]; a3 += row[j+3];
        }
        y = (a0 + a1) + (a2 + a3);
    }
    for (int it = 0; it < NPOW; ++it) {
        float n = y * y;
        #pragma unroll
        for (int off = 1; off < 64; off <<= 1) n += __shfl_xor(n, off, 64);
        float rn = rsqrtf(fmaxf(n, 1e-30f));
        vsh[lane] = y * rn;
        __syncthreads();
        const float4* vr = (const float4*)vsh;
        float a0 = 0, a1 = 0, a2 = 0, a3 = 0;
        #pragma unroll
        for (int j4 = 0; j4 < 16; ++j4) {
            float4 v4 = vr[j4];
            a0 = fmaf(row[4*j4+0], v4.x, a0);
            a1 = fmaf(row[4*j4+1], v4.y, a1);
            a2 = fmaf(row[4*j4+2], v4.z, a2);
            a3 = fmaf(row[4*j4+3], v4.w, a3);
        }
        y = (a0 + a1) + (a2 + a3);
        __syncthreads();
    }
    float lam = y * vsh[lane];
    #pragma unroll
    for (int off = 1; off < 64; off <<= 1) lam += __shfl_xor(lam, off, 64);
    if (lane == 0) {
        float l = fmaxf(lam, 0.f);
        eta[(size_t)b*SS + t] = 0.9f / (l + 1e-8f);
    }
}

// ---------------- fused ISTA (broadcast-grad, P-in-registers) ----------------
// thread = (row r = tid&7, s-slot sg = tid>>3). 8 lanes/wave share a K row
// (same-address broadcast). Each lane: grad dot + shrink for its (r, s=cb+sg),
// then folds d*K[s] into a register partial P[64]. One transpose-reduce per
// iteration (2 passes through Pbuf) replaces the per-chunk accum phase.
// R is updated incrementally: R += reduced(P)  (Qs folded into R at init).
__global__ __launch_bounds__(256, 2) void ista_kernel(
    const float* __restrict__ qsp, const float* __restrict__ ksp,
    const float* __restrict__ vp, const float* __restrict__ etap,
    float* __restrict__ out)
{
    __shared__ float  alpha[TM][APAD];   // 32896 B
    __shared__ float4 ksc[CHK * 17];     //  8704 B
    __shared__ float4 Pbuf[128][17];     // 34816 B (XOR-swizzled cols)
    __shared__ float  Rst[TM][68];       //  2176 B   total ~78.6 KB

    int bid = blockIdx.x;
    int b = bid & 7;
    int tile = (SS / TM - 1) - (bid >> 3);   // heavy tiles first
    int t0 = tile * TM;
    int Sact = t0 + TM;
    int nc = (Sact + CHK - 1) >> 5;
    int tid = threadIdx.x;

    int r  = tid & 7;          // row within tile
    int sg = tid >> 3;         // s-slot 0..31
    int trow = t0 + r;

    int rr = tid >> 5;         // reduce role: row 0..7
    int j2 = tid & 31;         // reduce role: column pair 0..31

    float eta_r = etap[(size_t)b*SS + trow];
    float thr_r = eta_r * SPARS;

    const float* ksb = ksp + (size_t)b * SS * DK;
    const float* vb  = vp  + (size_t)b * SS * DK;

    // init alpha = 0 ; Rst = -Qs (Ka starts at 0)
    for (int i = tid; i < TM * APAD; i += 256) ((float*)alpha)[i] = 0.f;
    if (tid < 128) {
        int r8 = tid >> 4, q = tid & 15;
        float4 qv = ((const float4*)(qsp + ((size_t)b*SS + t0) * DK))[tid];
        *(float4*)&Rst[r8][4*q] = make_float4(-qv.x, -qv.y, -qv.z, -qv.w);
    }
    __syncthreads();

    float Rr[64];
    float P[64];

    for (int it = 0; it < NITER; ++it) {
        // load this sweep's R row into registers (8-lane broadcast groups)
        #pragma unroll
        for (int j4 = 0; j4 < 16; ++j4) {
            float4 v = *(const float4*)&Rst[r][4*j4];
            Rr[4*j4+0] = v.x; Rr[4*j4+1] = v.y;
            Rr[4*j4+2] = v.z; Rr[4*j4+3] = v.w;
        }
        #pragma unroll
        for (int j = 0; j < 64; ++j) P[j] = 0.f;

        // prefetch chunk 0
        float4 ld0 = ((const float4*)ksb)[tid];
        float4 ld1 = ((const float4*)ksb)[tid + 256];

        for (int c = 0, cb = 0; c < nc; ++c, cb += CHK) {
            __syncthreads();                       // ksc consumers done
            ksc[(tid >> 4) * 17 + (tid & 15)] = ld0;
            {
                int i1 = tid + 256;
                ksc[(i1 >> 4) * 17 + (i1 & 15)] = ld1;
            }
            if (c + 1 < nc) {                      // T14: issue next loads now
                const float4* nx = (const float4*)(ksb + (size_t)(cb + CHK) * DK);
                ld0 = nx[tid]; ld1 = nx[tid + 256];
            }
            __syncthreads();

            int s = cb + sg;
            const float4* kp = &ksc[sg * 17];
            float4 kr[16];
            #pragma unroll
            for (int j4 = 0; j4 < 16; ++j4) kr[j4] = kp[j4];

            float g0 = 0, g1 = 0, g2 = 0, g3 = 0;
            #pragma unroll
            for (int j4 = 0; j4 < 16; ++j4) {
                g0 = fmaf(kr[j4].x, Rr[4*j4+0], g0);
                g1 = fmaf(kr[j4].y, Rr[4*j4+1], g1);
                g2 = fmaf(kr[j4].z, Rr[4*j4+2], g2);
                g3 = fmaf(kr[j4].w, Rr[4*j4+3], g3);
            }
            float grad = (g0 + g1) + (g2 + g3);
            float d = 0.f;
            if (s <= trow) {
                float a_old = alpha[r][s];
                float z = fmaf(-eta_r, grad, a_old);
                float az = fabsf(z) - thr_r;
                float an = az > 0.f ? copysignf(az, z) : 0.f;
                alpha[r][s] = an;
                d = an - a_old;
            }
            #pragma unroll
            for (int j4 = 0; j4 < 16; ++j4) {
                P[4*j4+0] = fmaf(d, kr[j4].x, P[4*j4+0]);
                P[4*j4+1] = fmaf(d, kr[j4].y, P[4*j4+1]);
                P[4*j4+2] = fmaf(d, kr[j4].z, P[4*j4+2]);
                P[4*j4+3] = fmaf(d, kr[j4].w, P[4*j4+3]);
            }
        }

        if (it == NITER - 1) break;   // no Ka/R update needed after last sweep

        // ---- reduce P over 32 s-lanes (2 passes), R += delta ----
        float accx = 0.f, accy = 0.f;
        if (tid < 128) {              // pass A: sg 0..15
            int key = sg & 7;
            #pragma unroll
            for (int j4 = 0; j4 < 16; ++j4) {
                int c4 = j4 ^ key;
                Pbuf[tid][c4] = make_float4(P[4*j4], P[4*j4+1], P[4*j4+2], P[4*j4+3]);
            }
        }
        __syncthreads();
        #pragma unroll
        for (int sgi = 0; sgi < 16; ++sgi) {
            int lt = sgi * 8 + rr;
            int c4 = (j2 >> 1) ^ (sgi & 7);
            const float* prow = (const float*)&Pbuf[lt][0];
            float2 v = *(const float2*)(prow + 4 * c4 + 2 * (j2 & 1));
            accx += v.x; accy += v.y;
        }
        __syncthreads();
        if (tid >= 128) {             // pass B: sg 16..31
            int lt = tid - 128;
            int key = (lt >> 3) & 7;
            #pragma unroll
            for (int j4 = 0; j4 < 16; ++j4) {
                int c4 = j4 ^ key;
                Pbuf[lt][c4] = make_float4(P[4*j4], P[4*j4+1], P[4*j4+2], P[4*j4+3]);
            }
        }
        __syncthreads();
        #pragma unroll
        for (int sgi = 0; sgi < 16; ++sgi) {
            int lt = sgi * 8 + rr;
            int c4 = (j2 >> 1) ^ (sgi & 7);
            const float* prow = (const float*)&Pbuf[lt][0];
            float2 v = *(const float2*)(prow + 4 * c4 + 2 * (j2 & 1));
            accx += v.x; accy += v.y;
        }
        Rst[rr][2*j2]     += accx;
        Rst[rr][2*j2 + 1] += accy;
        __syncthreads();              // R ready for next sweep's load
    }

    // ---- out = alpha @ V (same broadcast + P-reduce structure) ----
    #pragma unroll
    for (int j = 0; j < 64; ++j) P[j] = 0.f;
    {
        float4 ld0 = ((const float4*)vb)[tid];
        float4 ld1 = ((const float4*)vb)[tid + 256];
        for (int c = 0, cb = 0; c < nc; ++c, cb += CHK) {
            __syncthreads();
            ksc[(tid >> 4) * 17 + (tid & 15)] = ld0;
            {
                int i1 = tid + 256;
                ksc[(i1 >> 4) * 17 + (i1 & 15)] = ld1;
            }
            if (c + 1 < nc) {
                const float4* nx = (const float4*)(vb + (size_t)(cb + CHK) * DK);
                ld0 = nx[tid]; ld1 = nx[tid + 256];
            }
            __syncthreads();
            int s = cb + sg;
            float a = alpha[r][s];    // 0 beyond trow (never written)
            const float4* kp = &ksc[sg * 17];
            #pragma unroll
            for (int j4 = 0; j4 < 16; ++j4) {
                float4 kv = kp[j4];
                P[4*j4+0] = fmaf(a, kv.x, P[4*j4+0]);
                P[4*j4+1] = fmaf(a, kv.y, P[4*j4+1]);
                P[4*j4+2] = fmaf(a, kv.z, P[4*j4+2]);
                P[4*j4+3] = fmaf(a, kv.w, P[4*j4+3]);
            }
        }
    }
    __syncthreads();
    float accx = 0.f, accy = 0.f;
    if (tid < 128) {
        int key = sg & 7;
        #pragma unroll
        for (int j4 = 0; j4 < 16; ++j4) {
            int c4 = j4 ^ key;
            Pbuf[tid][c4] = make_float4(P[4*j4], P[4*j4+1], P[4*j4+2], P[4*j4+3]);
        }
    }
    __syncthreads();
    #pragma unroll
    for (int sgi = 0; sgi < 16; ++sgi) {
        int lt = sgi * 8 + rr;
        int c4 = (j2 >> 1) ^ (sgi & 7);
        const float* prow = (const float*)&Pbuf[lt][0];
        float2 v = *(const float2*)(prow + 4 * c4 + 2 * (j2 & 1));
        accx += v.x; accy += v.y;
    }
    __syncthreads();
    if (tid >= 128) {
        int lt = tid - 128;
        int key = (lt >> 3) & 7;
        #pragma unroll
        for (int j4 = 0; j4 < 16; ++j4) {
            int c4 = j4 ^ key;
            Pbuf[lt][c4] = make_float4(P[4*j4], P[4*j4+1], P[4*j4+2], P[4*j4+3]);
        }
    }
    __syncthreads();
    #pragma unroll
    for (int sgi = 0; sgi < 16; ++sgi) {
        int lt = sgi * 8 + rr;
        int c4 = (j2 >> 1) ^ (sgi & 7);
        const float* prow = (const float*)&Pbuf[lt][0];
        float2 v = *(const float2*)(prow + 4 * c4 + 2 * (j2 & 1));
        accx += v.x; accy += v.y;
    }
    *(float2*)(out + ((size_t)b*SS + t0 + rr) * DK + 2*j2) = make_float2(accx, accy);
}

extern "C" void kernel_launch(void* const* d_in, const int* in_sizes, int n_in,
                              void* d_out, int out_size, void* d_ws, size_t ws_size,
                              hipStream_t stream)
{
    const float* x  = (const float*)d_in[0];
    const float* Wq = (const float*)d_in[1];
    const float* bq = (const float*)d_in[2];
    const float* Wk = (const float*)d_in[3];
    const float* bk = (const float*)d_in[4];
    const float* Wv = (const float*)d_in[5];
    const float* bv = (const float*)d_in[6];
    float* out = (float*)d_out;

    float* w  = (float*)d_ws;
    float* qs = w;
    float* ks = w + (size_t)BB * SS * DK;
    float* v  = w + (size_t)2 * BB * SS * DK;
    float* gp = w + (size_t)3 * BB * SS * DK;           // [B][32][64][64]
    float* eta = gp + (size_t)BB * 32 * DK * DK;        // [B][S]

    hipLaunchKernelGGL(proj_kernel, dim3(BB * SS / 16), dim3(256), 0, stream,
                       x, Wq, bq, Wk, bk, Wv, bv, qs, ks, v);
    hipLaunchKernelGGL(gram_kernel, dim3(BB * 32), dim3(64), 0, stream, ks, gp);
    hipLaunchKernelGGL(prefix_kernel, dim3(BB), dim3(256), 0, stream, gp);
    hipLaunchKernelGGL(eigen_kernel, dim3(BB * SS), dim3(64), 0, stream, ks, gp, eta);
    hipLaunchKernelGGL(ista_kernel, dim3(BB * SS / TM), dim3(256), 0, stream,
                       qs, ks, v, eta, out);
}